// Round 16
// baseline (119.705 us; speedup 1.0000x reference)
//
#include <hip/hip_runtime.h>

#define CH 128
#define BN_EPS 1e-5f

typedef unsigned int uint32;
typedef unsigned short ushort16;
using f32x2  = __attribute__((ext_vector_type(2))) float;
using f32x4  = __attribute__((ext_vector_type(4))) float;
using bf16x8 = __attribute__((ext_vector_type(8))) short;

__device__ __forceinline__ ushort16 f2b(float f) {
    uint32 u = __float_as_uint(f);
    return (ushort16)((u + 0x7FFFu + ((u >> 16) & 1u)) >> 16);   // RNE
}
__device__ __forceinline__ uint32 pk2(float a, float b) {
    return (uint32)f2b(a) | ((uint32)f2b(b) << 16);
}
__device__ __forceinline__ float blo(uint32 u) { return __uint_as_float(u << 16); }
__device__ __forceinline__ float bhi(uint32 u) { return __uint_as_float(u & 0xFFFF0000u); }

// ---------------------------------------------------------------------------
// Init kernel: head[2N]=-1 (H=2 sub-chains per node), WcT bf16 build,
// bn zero, fp8 zero-row.
__global__ __launch_bounds__(256) void sage_init(
    const float* __restrict__ Wl, const float* __restrict__ Wr,
    int* __restrict__ head, ushort16* __restrict__ wct,
    float* __restrict__ bn, uint32* __restrict__ xqz, int nHead)
{
    int i = blockIdx.x * 256 + threadIdx.x;
    if (i < nHead) head[i] = -1;
    if (blockIdx.x < 128) {
        int widx = blockIdx.x * 256 + threadIdx.x;   // covers 128*256 = CH*256
        int co = widx >> 8, k = widx & 255;
        float v = (k < 128) ? Wr[co * 128 + k] : Wl[co * 128 + (k - 128)];
        wct[widx] = f2b(v);
    }
    if (blockIdx.x == 0) bn[threadIdx.x] = 0.f;      // bn_sum[128] + bn_sumsq[128]
    if (blockIdx.x == 1 && threadIdx.x < 32) xqz[threadIdx.x] = 0;  // zero fp8 row
}

// ---------------------------------------------------------------------------
// Prep: chain build (H=2: edge e with dst d links into head[(d<<1)|(e&1)])
// + converts. Atomic round-trip hides under convert work; pair store last.
__global__ __launch_bounds__(256) void sage_prep(
    const float* __restrict__ x, const void* __restrict__ ei,
    int* __restrict__ head, int2* __restrict__ pair,
    uint32* __restrict__ xb4, uint2* __restrict__ xq8,
    int nEdges, int total8)
{
    const int* pi = (const int*)ei;
    int lane = threadIdx.x & 63;
    bool is64 = (__ballot(pi[lane * 2 + 1] != 0) == 0ULL);

    int idx = blockIdx.x * 256 + threadIdx.x;
    bool hasE = (idx < nEdges);
    bool hasC = (idx < total8);

    int s = 0, d = 0;
    if (hasE) {
        if (is64) {
            const long long* p = (const long long*)ei;
            s = (int)p[idx];
            d = (int)p[nEdges + idx];
        } else {
            s = pi[idx];
            d = pi[nEdges + idx];
        }
    }
    const float4* x4 = (const float4*)x;
    float4 a = make_float4(0, 0, 0, 0), b = make_float4(0, 0, 0, 0);
    if (hasC) { a = x4[2 * idx]; b = x4[2 * idx + 1]; }

    int old = 0;
    if (hasE) old = atomicExch(&head[(d << 1) | (idx & 1)], idx);

    if (hasC) {
        uint4 o;
        o.x = pk2(a.x, a.y); o.y = pk2(a.z, a.w);
        o.z = pk2(b.x, b.y); o.w = pk2(b.z, b.w);
        ((uint4*)xb4)[idx] = o;

        int qa = __builtin_amdgcn_cvt_pk_fp8_f32(a.x, a.y, 0, false);
        qa = __builtin_amdgcn_cvt_pk_fp8_f32(a.z, a.w, qa, true);
        int qb = __builtin_amdgcn_cvt_pk_fp8_f32(b.x, b.y, 0, false);
        qb = __builtin_amdgcn_cvt_pk_fp8_f32(b.z, b.w, qb, true);
        xq8[idx] = make_uint2((uint32)qa, (uint32)qb);
    }

    if (hasE) pair[idx] = make_int2(old, s);
}

// ---------------------------------------------------------------------------
// Chain-walk gather, H=2: 8 nodes/wave = 16 sub-chains (avg length ~8,
// E[max] ~13-15 vs ~22-24 for 8 chains of 16 -> 40% fewer iterations).
//  - walkers in lanes 0-15; head load is one coalesced 16-int read.
//  - per step: 1 masked pair[] gather (16 lanes) + TWO packed row loads
//    (rowA covers sub-chains 0-7, rowB covers 8-15) = 3 VMEM per 16 edges.
//  - parity pairs (sub-chains 2m, 2m+1) merge via shfl_xor(.,8) at the end.
__global__ __launch_bounds__(256) void sage_aggregate(
    const char* __restrict__ xq, const int* __restrict__ head,
    const int2* __restrict__ pair, uint32* __restrict__ mean_b, int nNodes)
{
    int wid = blockIdx.x * 4 + (threadIdx.x >> 6);
    int nbase = wid * 8;
    if (nbase >= nNodes) return;
    int lane = threadIdx.x & 63;
    int grp = lane >> 3;             // 0..7
    int sub = lane & 7;              // 16B slot within the 128B row

    const int ZROW = nNodes;         // zeroed fp8 row

    // walker lane l (<16) handles sub-chain l: node nbase+(l>>1), parity l&1
    int cur = -1;
    if (lane < 16) {
        int n = nbase + (lane >> 1);
        if (n < nNodes) cur = head[((size_t)n << 1) | (lane & 1)];
    }
    int cnt = 0;
    f32x2 aA[8], aB[8];              // accA: sub-chain grp; accB: 8+grp
    #pragma unroll
    for (int i = 0; i < 8; ++i) { aA[i] = (f32x2){0.f, 0.f}; aB[i] = (f32x2){0.f, 0.f}; }

    int2 pr = make_int2(-1, ZROW);
    if (cur >= 0) pr = pair[cur];

    while (__ballot(cur >= 0) != 0ULL) {
        int nxt = pr.x;
        int2 prn = make_int2(-1, ZROW);
        if (cur >= 0 && nxt >= 0) prn = pair[nxt];    // prefetch next hop

        int sA = __shfl(pr.y, grp);                   // sub-chain grp's src
        int sB = __shfl(pr.y, 8 + grp);               // sub-chain 8+grp's src
        uint4 uA = *(const uint4*)(xq + ((size_t)sA << 7) + sub * 16);
        uint4 uB = *(const uint4*)(xq + ((size_t)sB << 7) + sub * 16);
        #pragma unroll
        for (int w = 0; w < 4; ++w) {
            uint32 wA = (&uA.x)[w], wB = (&uB.x)[w];
            aA[w * 2 + 0] += __builtin_amdgcn_cvt_pk_f32_fp8((int)wA, false);
            aA[w * 2 + 1] += __builtin_amdgcn_cvt_pk_f32_fp8((int)wA, true);
            aB[w * 2 + 0] += __builtin_amdgcn_cvt_pk_f32_fp8((int)wB, false);
            aB[w * 2 + 1] += __builtin_amdgcn_cvt_pk_f32_fp8((int)wB, true);
        }
        if (cur >= 0) { ++cnt; cur = nxt; }
        pr = prn;
    }

    // merge parity pairs: lane l's partner l^8 holds the sibling sub-chain
    #pragma unroll
    for (int i = 0; i < 8; ++i) {
        aA[i][0] += __shfl_xor(aA[i][0], 8);
        aA[i][1] += __shfl_xor(aA[i][1], 8);
        aB[i][0] += __shfl_xor(aB[i][0], 8);
        aB[i][1] += __shfl_xor(aB[i][1], 8);
    }
    int cA = __shfl(cnt, grp & ~1) + __shfl(cnt, grp | 1);
    int cB = __shfl(cnt, 8 + (grp & ~1)) + __shfl(cnt, 8 + (grp | 1));

    if ((grp & 1) == 0) {
        float invA = 1.0f / fmaxf((float)cA, 1.0f);
        int nA = nbase + (grp >> 1);
        if (nA < nNodes) {
            uint4 o0 = make_uint4(pk2(aA[0][0] * invA, aA[0][1] * invA),
                                  pk2(aA[1][0] * invA, aA[1][1] * invA),
                                  pk2(aA[2][0] * invA, aA[2][1] * invA),
                                  pk2(aA[3][0] * invA, aA[3][1] * invA));
            uint4 o1 = make_uint4(pk2(aA[4][0] * invA, aA[4][1] * invA),
                                  pk2(aA[5][0] * invA, aA[5][1] * invA),
                                  pk2(aA[6][0] * invA, aA[6][1] * invA),
                                  pk2(aA[7][0] * invA, aA[7][1] * invA));
            char* base = (char*)mean_b + (size_t)nA * 256 + sub * 32;
            *(uint4*)base = o0;
            *(uint4*)(base + 16) = o1;
        }
        float invB = 1.0f / fmaxf((float)cB, 1.0f);
        int nB = nbase + 4 + (grp >> 1);
        if (nB < nNodes) {
            uint4 o0 = make_uint4(pk2(aB[0][0] * invB, aB[0][1] * invB),
                                  pk2(aB[1][0] * invB, aB[1][1] * invB),
                                  pk2(aB[2][0] * invB, aB[2][1] * invB),
                                  pk2(aB[3][0] * invB, aB[3][1] * invB));
            uint4 o1 = make_uint4(pk2(aB[4][0] * invB, aB[4][1] * invB),
                                  pk2(aB[5][0] * invB, aB[5][1] * invB),
                                  pk2(aB[6][0] * invB, aB[6][1] * invB),
                                  pk2(aB[7][0] * invB, aB[7][1] * invB));
            char* base = (char*)mean_b + (size_t)nB * 256 + sub * 32;
            *(uint4*)base = o0;
            *(uint4*)(base + 16) = o1;
        }
    }
}

// ---------------------------------------------------------------------------
// GEMM (R13-proven): K=256, 128 rows per block (two 16-row tiles per wave).
// wct staged in LDS in fragment order; each ds_read_b128 feeds TWO MFMAs.
// h stored bf16; fused BN partials -> one atomicAdd per channel per block.
__global__ __launch_bounds__(256) void sage_gemm(
    const ushort16* __restrict__ xb, const ushort16* __restrict__ mean_b,
    const ushort16* __restrict__ wct, const float* __restrict__ bl,
    ushort16* __restrict__ hb, float* __restrict__ bn, int nNodes)
{
    __shared__ ushort16 wsh[8 * 8 * 64 * 8];   // 64 KB, fragment-ordered
    __shared__ float redS[4][CH];
    __shared__ float redQ[4][CH];

    int tid = threadIdx.x;
    int wave = tid >> 6, lane = tid & 63;
    int col = lane & 15, kg = lane >> 4;

    #pragma unroll
    for (int it = 0; it < 16; ++it) {
        int pidx = wave * 16 + it;               // pidx = cb*8 + kstep
        int cb = pidx >> 3, ks = pidx & 7;
        bf16x8 v = *(const bf16x8*)(wct + (size_t)(cb * 16 + col) * 256 + ks * 32 + kg * 8);
        *(bf16x8*)(wsh + ((size_t)pidx * 64 + lane) * 8) = v;
    }

    int row0 = blockIdx.x * 128 + wave * 16;            // tile 0
    int row1 = row0 + 64;                               // tile 1
    int arow0 = min(row0 + col, nNodes - 1);
    int arow1 = min(row1 + col, nNodes - 1);
    const ushort16* xr0 = xb + (size_t)arow0 * CH;
    const ushort16* mr0 = mean_b + (size_t)arow0 * CH;
    const ushort16* xr1 = xb + (size_t)arow1 * CH;
    const ushort16* mr1 = mean_b + (size_t)arow1 * CH;

    bf16x8 af0[8], af1[8];
    #pragma unroll
    for (int t = 0; t < 4; ++t) {
        af0[t]     = *(const bf16x8*)(xr0 + t * 32 + kg * 8);
        af0[4 + t] = *(const bf16x8*)(mr0 + t * 32 + kg * 8);
        af1[t]     = *(const bf16x8*)(xr1 + t * 32 + kg * 8);
        af1[4 + t] = *(const bf16x8*)(mr1 + t * 32 + kg * 8);
    }

    __syncthreads();

    f32x4 acc0[8], acc1[8];
    #pragma unroll
    for (int cb = 0; cb < 8; ++cb) {
        acc0[cb] = (f32x4){0.f, 0.f, 0.f, 0.f};
        acc1[cb] = (f32x4){0.f, 0.f, 0.f, 0.f};
    }

    #pragma unroll
    for (int kstep = 0; kstep < 8; ++kstep) {
        #pragma unroll
        for (int cb = 0; cb < 8; ++cb) {
            bf16x8 b = *(const bf16x8*)(wsh + ((size_t)(cb * 8 + kstep) * 64 + lane) * 8);
            acc0[cb] = __builtin_amdgcn_mfma_f32_16x16x32_bf16(af0[kstep], b, acc0[cb], 0, 0, 0);
            acc1[cb] = __builtin_amdgcn_mfma_f32_16x16x32_bf16(af1[kstep], b, acc1[cb], 0, 0, 0);
        }
    }

    #pragma unroll
    for (int cb = 0; cb < 8; ++cb) {
        int co = cb * 16 + col;
        float blv = bl[co];
        float s = 0.f, ss = 0.f;
        #pragma unroll
        for (int j = 0; j < 4; ++j) {
            int r0 = row0 + kg * 4 + j;                 // C row = (lane>>4)*4+j
            float v0 = acc0[cb][j] + blv;
            if (r0 < nNodes) {
                hb[(size_t)r0 * CH + co] = f2b(v0);
                s += v0; ss += v0 * v0;
            }
            int r1 = row1 + kg * 4 + j;
            float v1 = acc1[cb][j] + blv;
            if (r1 < nNodes) {
                hb[(size_t)r1 * CH + co] = f2b(v1);
                s += v1; ss += v1 * v1;
            }
        }
        s  += __shfl_xor(s, 16);  s  += __shfl_xor(s, 32);
        ss += __shfl_xor(ss, 16); ss += __shfl_xor(ss, 32);
        if (kg == 0) { redS[wave][co] = s; redQ[wave][co] = ss; }
    }
    __syncthreads();
    if (tid < CH) {
        atomicAdd(&bn[tid], redS[0][tid] + redS[1][tid] + redS[2][tid] + redS[3][tid]);
    } else {
        int c = tid - CH;
        atomicAdd(&bn[CH + c], redQ[0][c] + redQ[1][c] + redQ[2][c] + redQ[3][c]);
    }
}

// ---------------------------------------------------------------------------
// Fused BN-finalize + apply: reads bf16 h (8 ch/thread), writes f32 d_out.
__global__ __launch_bounds__(256) void sage_apply(
    const ushort16* __restrict__ hb, float* __restrict__ out,
    const float* __restrict__ bn, const float* __restrict__ gamma,
    const float* __restrict__ beta, int total8, int nNodes)
{
    __shared__ float sc_sh[CH], sh_sh[CH];
    int tid = threadIdx.x;
    if (tid < CH) {
        float invN = 1.0f / (float)nNodes;
        float mu = bn[tid] * invN;
        float var = fmaxf(bn[CH + tid] * invN - mu * mu, 0.f);
        float sc = gamma[tid] * rsqrtf(var + BN_EPS);
        sc_sh[tid] = sc;
        sh_sh[tid] = beta[tid] - mu * sc;
    }
    __syncthreads();
    int i = blockIdx.x * 256 + tid;
    if (i >= total8) return;
    uint4 u = *(const uint4*)(hb + (size_t)i * 8);
    int c = (i * 8) & 127;
    float4 o0, o1;
    o0.x = fmaxf(fmaf(blo(u.x), sc_sh[c + 0], sh_sh[c + 0]), 0.f);
    o0.y = fmaxf(fmaf(bhi(u.x), sc_sh[c + 1], sh_sh[c + 1]), 0.f);
    o0.z = fmaxf(fmaf(blo(u.y), sc_sh[c + 2], sh_sh[c + 2]), 0.f);
    o0.w = fmaxf(fmaf(bhi(u.y), sc_sh[c + 3], sh_sh[c + 3]), 0.f);
    o1.x = fmaxf(fmaf(blo(u.z), sc_sh[c + 4], sh_sh[c + 4]), 0.f);
    o1.y = fmaxf(fmaf(bhi(u.z), sc_sh[c + 5], sh_sh[c + 5]), 0.f);
    o1.z = fmaxf(fmaf(blo(u.w), sc_sh[c + 6], sh_sh[c + 6]), 0.f);
    o1.w = fmaxf(fmaf(bhi(u.w), sc_sh[c + 7], sh_sh[c + 7]), 0.f);
    float4* dst = (float4*)(out + (size_t)i * 8);
    dst[0] = o0;
    dst[1] = o1;
}

// ---------------------------------------------------------------------------
extern "C" void kernel_launch(void* const* d_in, const int* in_sizes, int n_in,
                              void* d_out, int out_size, void* d_ws, size_t ws_size,
                              hipStream_t stream)
{
    const float* x     = (const float*)d_in[0];
    const void*  ei    = d_in[1];
    const float* Wl    = (const float*)d_in[2];
    const float* bl    = (const float*)d_in[3];
    const float* Wr    = (const float*)d_in[4];
    const float* gamma = (const float*)d_in[5];
    const float* beta  = (const float*)d_in[6];

    int nNodes = in_sizes[0] / CH;
    int nEdges = in_sizes[1] / 2;
    int nHead  = nNodes * 2;               // H=2 sub-chains per node
    int nBlkM  = (nNodes + 127) / 128;

    // ws layout (256B-aligned slabs); ws_size = 256 MiB
    char* p = (char*)d_ws;
    auto take = [&](size_t bytes) {
        char* r = p;
        p += (bytes + 255) & ~(size_t)255;
        return r;
    };
    ushort16* xb      = (ushort16*)take((size_t)nNodes * CH * 2);      // 12.8 MB
    char*     xq      = (char*)take((size_t)nNodes * CH + 128);        // 6.4 MB fp8 + zero row
    ushort16* mean_b  = (ushort16*)take((size_t)nNodes * CH * 2);      // 12.8 MB
    ushort16* hb      = (ushort16*)take((size_t)nNodes * CH * 2);      // 12.8 MB bf16 h
    ushort16* wct     = (ushort16*)take((size_t)CH * 256 * 2);         // 64 KB
    int*      head    = (int*)take((size_t)nHead * 4);                 // 400 KB
    float*    bn      = (float*)take(256 * 4);
    int2*     pair    = (int2*)take((size_t)nEdges * 8);               // 6.4 MB

    float* out = (float*)d_out;

    int total8 = nNodes * CH / 8;
    int eBlocks = (nEdges + 255) / 256;
    int pBlocks = max(eBlocks, (total8 + 255) / 256);
    int iBlocks = max((nHead + 255) / 256, 128);

    sage_init<<<iBlocks, 256, 0, stream>>>(
        Wl, Wr, head, wct, bn, (uint32*)(xq + (size_t)nNodes * CH), nHead);

    sage_prep<<<pBlocks, 256, 0, stream>>>(
        x, ei, head, pair, (uint32*)xb, (uint2*)xq, nEdges, total8);

    int aBlocks = (nNodes + 31) / 32;   // 8 nodes/wave, 4 waves/block
    sage_aggregate<<<aBlocks, 256, 0, stream>>>(
        xq, head, pair, (uint32*)mean_b, nNodes);

    sage_gemm<<<nBlkM, 256, 0, stream>>>(
        xb, mean_b, wct, bl, hb, bn, nNodes);

    sage_apply<<<(total8 + 255) / 256, 256, 0, stream>>>(
        hb, out, bn, gamma, beta, total8, nNodes);
}

// Round 17
// 113.428 us; speedup vs baseline: 1.0553x; 1.0553x over previous
//
#include <hip/hip_runtime.h>

#define CH 128
#define BN_EPS 1e-5f

typedef unsigned int uint32;
typedef unsigned short ushort16;
using f32x2  = __attribute__((ext_vector_type(2))) float;
using f32x4  = __attribute__((ext_vector_type(4))) float;
using bf16x8 = __attribute__((ext_vector_type(8))) short;

__device__ __forceinline__ ushort16 f2b(float f) {
    uint32 u = __float_as_uint(f);
    return (ushort16)((u + 0x7FFFu + ((u >> 16) & 1u)) >> 16);   // RNE
}
__device__ __forceinline__ uint32 pk2(float a, float b) {
    return (uint32)f2b(a) | ((uint32)f2b(b) << 16);
}
__device__ __forceinline__ float blo(uint32 u) { return __uint_as_float(u << 16); }
__device__ __forceinline__ float bhi(uint32 u) { return __uint_as_float(u & 0xFFFF0000u); }

// ---------------------------------------------------------------------------
// Init kernel: head=-1, WcT bf16 build, bn zero, fp8 zero-row.
__global__ __launch_bounds__(256) void sage_init(
    const float* __restrict__ Wl, const float* __restrict__ Wr,
    int* __restrict__ head, ushort16* __restrict__ wct,
    float* __restrict__ bn, uint32* __restrict__ xqz, int nNodes)
{
    int i = blockIdx.x * 256 + threadIdx.x;
    if (i < nNodes) head[i] = -1;
    if (blockIdx.x < 128) {
        int widx = blockIdx.x * 256 + threadIdx.x;   // covers 128*256 = CH*256
        int co = widx >> 8, k = widx & 255;
        float v = (k < 128) ? Wr[co * 128 + k] : Wl[co * 128 + (k - 128)];
        wct[widx] = f2b(v);
    }
    if (blockIdx.x == 0) bn[threadIdx.x] = 0.f;      // bn_sum[128] + bn_sumsq[128]
    if (blockIdx.x == 1 && threadIdx.x < 32) xqz[threadIdx.x] = 0;  // zero fp8 row
}

// ---------------------------------------------------------------------------
// Prep: chain build + converts. Order: ei loads -> x loads -> atomicExch ->
// convert stores (atomic still in flight) -> pair store last.
__global__ __launch_bounds__(256) void sage_prep(
    const float* __restrict__ x, const void* __restrict__ ei,
    int* __restrict__ head, int2* __restrict__ pair,
    uint32* __restrict__ xb4, uint2* __restrict__ xq8,
    int nEdges, int total8)
{
    const int* pi = (const int*)ei;
    int lane = threadIdx.x & 63;
    bool is64 = (__ballot(pi[lane * 2 + 1] != 0) == 0ULL);

    int idx = blockIdx.x * 256 + threadIdx.x;
    bool hasE = (idx < nEdges);
    bool hasC = (idx < total8);

    int s = 0, d = 0;
    if (hasE) {
        if (is64) {
            const long long* p = (const long long*)ei;
            s = (int)p[idx];
            d = (int)p[nEdges + idx];
        } else {
            s = pi[idx];
            d = pi[nEdges + idx];
        }
    }
    const float4* x4 = (const float4*)x;
    float4 a = make_float4(0, 0, 0, 0), b = make_float4(0, 0, 0, 0);
    if (hasC) { a = x4[2 * idx]; b = x4[2 * idx + 1]; }

    int old = 0;
    if (hasE) old = atomicExch(&head[d], idx);

    if (hasC) {
        uint4 o;
        o.x = pk2(a.x, a.y); o.y = pk2(a.z, a.w);
        o.z = pk2(b.x, b.y); o.w = pk2(b.z, b.w);
        ((uint4*)xb4)[idx] = o;

        int qa = __builtin_amdgcn_cvt_pk_fp8_f32(a.x, a.y, 0, false);
        qa = __builtin_amdgcn_cvt_pk_fp8_f32(a.z, a.w, qa, true);
        int qb = __builtin_amdgcn_cvt_pk_fp8_f32(b.x, b.y, 0, false);
        qb = __builtin_amdgcn_cvt_pk_fp8_f32(b.z, b.w, qb, true);
        xq8[idx] = make_uint2((uint32)qa, (uint32)qb);
    }

    if (hasE) pair[idx] = make_int2(old, s);
}

// ---------------------------------------------------------------------------
// Chain-walk gather (best of 5 variants): 8 chains/wave, 2 VMEM/step
// (8 edges), fp8 rows, pair prefetch pipelined. NO LDS -> full occupancy.
__global__ __launch_bounds__(256) void sage_aggregate(
    const char* __restrict__ xq, const int* __restrict__ head,
    const int2* __restrict__ pair, uint32* __restrict__ mean_b, int nNodes)
{
    int wid = blockIdx.x * 4 + (threadIdx.x >> 6);
    int nbase = wid * 8;
    if (nbase >= nNodes) return;
    int lane = threadIdx.x & 63;
    int chain = lane >> 3;           // 0..7
    int sub = lane & 7;              // 16B slot within the 128B row

    const int ZROW = nNodes;         // zeroed fp8 row

    int cur = -1;
    if (lane < 8) {
        int n = nbase + lane;
        cur = (n < nNodes) ? head[n] : -1;
    }
    int cnt = 0;
    f32x2 acc2[8];
    #pragma unroll
    for (int i = 0; i < 8; ++i) acc2[i] = (f32x2){0.f, 0.f};

    int2 pr = make_int2(-1, ZROW);
    if (cur >= 0) pr = pair[cur];

    while (__ballot(cur >= 0) != 0ULL) {
        int nxt = pr.x;
        int2 prn = make_int2(-1, ZROW);
        if (cur >= 0 && nxt >= 0) prn = pair[nxt];    // prefetch next hop

        int s = __shfl(pr.y, chain);                  // my chain's src row
        uint4 u = *(const uint4*)(xq + ((size_t)s << 7) + sub * 16);
        #pragma unroll
        for (int w = 0; w < 4; ++w) {
            uint32 uw = (&u.x)[w];
            acc2[w * 2 + 0] += __builtin_amdgcn_cvt_pk_f32_fp8((int)uw, false);
            acc2[w * 2 + 1] += __builtin_amdgcn_cvt_pk_f32_fp8((int)uw, true);
        }
        if (cur >= 0) { ++cnt; cur = nxt; }
        pr = prn;
    }

    int cn = __shfl(cnt, chain);
    float inv = 1.0f / fmaxf((float)cn, 1.0f);
    int n = nbase + chain;
    if (n < nNodes) {
        uint4 o0 = make_uint4(pk2(acc2[0][0] * inv, acc2[0][1] * inv),
                              pk2(acc2[1][0] * inv, acc2[1][1] * inv),
                              pk2(acc2[2][0] * inv, acc2[2][1] * inv),
                              pk2(acc2[3][0] * inv, acc2[3][1] * inv));
        uint4 o1 = make_uint4(pk2(acc2[4][0] * inv, acc2[4][1] * inv),
                              pk2(acc2[5][0] * inv, acc2[5][1] * inv),
                              pk2(acc2[6][0] * inv, acc2[6][1] * inv),
                              pk2(acc2[7][0] * inv, acc2[7][1] * inv));
        char* base = (char*)mean_b + (size_t)n * 256 + sub * 32;
        *(uint4*)base = o0;
        *(uint4*)(base + 16) = o1;
    }
}

// ---------------------------------------------------------------------------
// GEMM: K=256, 128 rows per block (two 16-row tiles per wave).
// wct staged in LDS in fragment order; each ds_read_b128 feeds TWO MFMAs.
// h stored bf16; fused BN partials -> one atomicAdd per channel per block.
__global__ __launch_bounds__(256) void sage_gemm(
    const ushort16* __restrict__ xb, const ushort16* __restrict__ mean_b,
    const ushort16* __restrict__ wct, const float* __restrict__ bl,
    ushort16* __restrict__ hb, float* __restrict__ bn, int nNodes)
{
    __shared__ ushort16 wsh[8 * 8 * 64 * 8];   // 64 KB, fragment-ordered
    __shared__ float redS[4][CH];
    __shared__ float redQ[4][CH];

    int tid = threadIdx.x;
    int wave = tid >> 6, lane = tid & 63;
    int col = lane & 15, kg = lane >> 4;

    #pragma unroll
    for (int it = 0; it < 16; ++it) {
        int pidx = wave * 16 + it;               // pidx = cb*8 + kstep
        int cb = pidx >> 3, ks = pidx & 7;
        bf16x8 v = *(const bf16x8*)(wct + (size_t)(cb * 16 + col) * 256 + ks * 32 + kg * 8);
        *(bf16x8*)(wsh + ((size_t)pidx * 64 + lane) * 8) = v;
    }

    int row0 = blockIdx.x * 128 + wave * 16;            // tile 0
    int row1 = row0 + 64;                               // tile 1
    int arow0 = min(row0 + col, nNodes - 1);
    int arow1 = min(row1 + col, nNodes - 1);
    const ushort16* xr0 = xb + (size_t)arow0 * CH;
    const ushort16* mr0 = mean_b + (size_t)arow0 * CH;
    const ushort16* xr1 = xb + (size_t)arow1 * CH;
    const ushort16* mr1 = mean_b + (size_t)arow1 * CH;

    bf16x8 af0[8], af1[8];
    #pragma unroll
    for (int t = 0; t < 4; ++t) {
        af0[t]     = *(const bf16x8*)(xr0 + t * 32 + kg * 8);
        af0[4 + t] = *(const bf16x8*)(mr0 + t * 32 + kg * 8);
        af1[t]     = *(const bf16x8*)(xr1 + t * 32 + kg * 8);
        af1[4 + t] = *(const bf16x8*)(mr1 + t * 32 + kg * 8);
    }

    __syncthreads();

    f32x4 acc0[8], acc1[8];
    #pragma unroll
    for (int cb = 0; cb < 8; ++cb) {
        acc0[cb] = (f32x4){0.f, 0.f, 0.f, 0.f};
        acc1[cb] = (f32x4){0.f, 0.f, 0.f, 0.f};
    }

    #pragma unroll
    for (int kstep = 0; kstep < 8; ++kstep) {
        #pragma unroll
        for (int cb = 0; cb < 8; ++cb) {
            bf16x8 b = *(const bf16x8*)(wsh + ((size_t)(cb * 8 + kstep) * 64 + lane) * 8);
            acc0[cb] = __builtin_amdgcn_mfma_f32_16x16x32_bf16(af0[kstep], b, acc0[cb], 0, 0, 0);
            acc1[cb] = __builtin_amdgcn_mfma_f32_16x16x32_bf16(af1[kstep], b, acc1[cb], 0, 0, 0);
        }
    }

    #pragma unroll
    for (int cb = 0; cb < 8; ++cb) {
        int co = cb * 16 + col;
        float blv = bl[co];
        float s = 0.f, ss = 0.f;
        #pragma unroll
        for (int j = 0; j < 4; ++j) {
            int r0 = row0 + kg * 4 + j;                 // C row = (lane>>4)*4+j
            float v0 = acc0[cb][j] + blv;
            if (r0 < nNodes) {
                hb[(size_t)r0 * CH + co] = f2b(v0);
                s += v0; ss += v0 * v0;
            }
            int r1 = row1 + kg * 4 + j;
            float v1 = acc1[cb][j] + blv;
            if (r1 < nNodes) {
                hb[(size_t)r1 * CH + co] = f2b(v1);
                s += v1; ss += v1 * v1;
            }
        }
        s  += __shfl_xor(s, 16);  s  += __shfl_xor(s, 32);
        ss += __shfl_xor(ss, 16); ss += __shfl_xor(ss, 32);
        if (kg == 0) { redS[wave][co] = s; redQ[wave][co] = ss; }
    }
    __syncthreads();
    if (tid < CH) {
        atomicAdd(&bn[tid], redS[0][tid] + redS[1][tid] + redS[2][tid] + redS[3][tid]);
    } else {
        int c = tid - CH;
        atomicAdd(&bn[CH + c], redQ[0][c] + redQ[1][c] + redQ[2][c] + redQ[3][c]);
    }
}

// ---------------------------------------------------------------------------
// Fused BN-finalize + apply: reads bf16 h (8 ch/thread), writes f32 d_out.
__global__ __launch_bounds__(256) void sage_apply(
    const ushort16* __restrict__ hb, float* __restrict__ out,
    const float* __restrict__ bn, const float* __restrict__ gamma,
    const float* __restrict__ beta, int total8, int nNodes)
{
    __shared__ float sc_sh[CH], sh_sh[CH];
    int tid = threadIdx.x;
    if (tid < CH) {
        float invN = 1.0f / (float)nNodes;
        float mu = bn[tid] * invN;
        float var = fmaxf(bn[CH + tid] * invN - mu * mu, 0.f);
        float sc = gamma[tid] * rsqrtf(var + BN_EPS);
        sc_sh[tid] = sc;
        sh_sh[tid] = beta[tid] - mu * sc;
    }
    __syncthreads();
    int i = blockIdx.x * 256 + tid;
    if (i >= total8) return;
    uint4 u = *(const uint4*)(hb + (size_t)i * 8);
    int c = (i * 8) & 127;
    float4 o0, o1;
    o0.x = fmaxf(fmaf(blo(u.x), sc_sh[c + 0], sh_sh[c + 0]), 0.f);
    o0.y = fmaxf(fmaf(bhi(u.x), sc_sh[c + 1], sh_sh[c + 1]), 0.f);
    o0.z = fmaxf(fmaf(blo(u.y), sc_sh[c + 2], sh_sh[c + 2]), 0.f);
    o0.w = fmaxf(fmaf(bhi(u.y), sc_sh[c + 3], sh_sh[c + 3]), 0.f);
    o1.x = fmaxf(fmaf(blo(u.z), sc_sh[c + 4], sh_sh[c + 4]), 0.f);
    o1.y = fmaxf(fmaf(bhi(u.z), sc_sh[c + 5], sh_sh[c + 5]), 0.f);
    o1.z = fmaxf(fmaf(blo(u.w), sc_sh[c + 6], sh_sh[c + 6]), 0.f);
    o1.w = fmaxf(fmaf(bhi(u.w), sc_sh[c + 7], sh_sh[c + 7]), 0.f);
    float4* dst = (float4*)(out + (size_t)i * 8);
    dst[0] = o0;
    dst[1] = o1;
}

// ---------------------------------------------------------------------------
extern "C" void kernel_launch(void* const* d_in, const int* in_sizes, int n_in,
                              void* d_out, int out_size, void* d_ws, size_t ws_size,
                              hipStream_t stream)
{
    const float* x     = (const float*)d_in[0];
    const void*  ei    = d_in[1];
    const float* Wl    = (const float*)d_in[2];
    const float* bl    = (const float*)d_in[3];
    const float* Wr    = (const float*)d_in[4];
    const float* gamma = (const float*)d_in[5];
    const float* beta  = (const float*)d_in[6];

    int nNodes = in_sizes[0] / CH;
    int nEdges = in_sizes[1] / 2;
    int nBlkM  = (nNodes + 127) / 128;

    // ws layout (256B-aligned slabs); ws_size = 256 MiB
    char* p = (char*)d_ws;
    auto take = [&](size_t bytes) {
        char* r = p;
        p += (bytes + 255) & ~(size_t)255;
        return r;
    };
    ushort16* xb      = (ushort16*)take((size_t)nNodes * CH * 2);      // 12.8 MB
    char*     xq      = (char*)take((size_t)nNodes * CH + 128);        // 6.4 MB fp8 + zero row
    ushort16* mean_b  = (ushort16*)take((size_t)nNodes * CH * 2);      // 12.8 MB
    ushort16* hb      = (ushort16*)take((size_t)nNodes * CH * 2);      // 12.8 MB bf16 h
    ushort16* wct     = (ushort16*)take((size_t)CH * 256 * 2);         // 64 KB
    int*      head    = (int*)take((size_t)nNodes * 4);
    float*    bn      = (float*)take(256 * 4);
    int2*     pair    = (int2*)take((size_t)nEdges * 8);               // 6.4 MB

    float* out = (float*)d_out;

    int total8 = nNodes * CH / 8;
    int eBlocks = (nEdges + 255) / 256;
    int pBlocks = max(eBlocks, (total8 + 255) / 256);
    int iBlocks = max((nNodes + 255) / 256, 128);

    sage_init<<<iBlocks, 256, 0, stream>>>(
        Wl, Wr, head, wct, bn, (uint32*)(xq + (size_t)nNodes * CH), nNodes);

    sage_prep<<<pBlocks, 256, 0, stream>>>(
        x, ei, head, pair, (uint32*)xb, (uint2*)xq, nEdges, total8);

    int aBlocks = (nNodes + 31) / 32;   // 8 nodes/wave, 4 waves/block
    sage_aggregate<<<aBlocks, 256, 0, stream>>>(
        xq, head, pair, (uint32*)mean_b, nNodes);

    sage_gemm<<<nBlkM, 256, 0, stream>>>(
        xb, mean_b, wct, bl, hb, bn, nNodes);

    sage_apply<<<(total8 + 255) / 256, 256, 0, stream>>>(
        hb, out, bn, gamma, beta, total8, nNodes);
}